// Round 3
// baseline (1157.400 us; speedup 1.0000x reference)
//
#include <hip/hip_runtime.h>
#include <hip/hip_bf16.h>

typedef unsigned int u32;
typedef unsigned short u16;
typedef short bf16x8 __attribute__((ext_vector_type(8)));
typedef float f32x4 __attribute__((ext_vector_type(4)));

#define DEVFN static __device__ __forceinline__

DEVFN u16 f2bf(float f) {
  u32 u = __builtin_bit_cast(u32, f);
  u = (u + 0x7fffu + ((u >> 16) & 1u)) >> 16;
  return (u16)u;
}
DEVFN u32 pk2(float a, float b) { return (u32)f2bf(a) | ((u32)f2bf(b) << 16); }
DEVFN float blo(u32 w) { return __builtin_bit_cast(float, w << 16); }
DEVFN float bhi(u32 w) { return __builtin_bit_cast(float, w & 0xffff0000u); }

// load 8 consecutive f32 and pack to 8 bf16 (one uint4)
DEVFN uint4 cvt8(const float* p) {
  f32x4 v0 = *(const f32x4*)p;
  f32x4 v1 = *(const f32x4*)(p + 4);
  uint4 o;
  o.x = pk2(v0.x, v0.y); o.y = pk2(v0.z, v0.w);
  o.z = pk2(v1.x, v1.y); o.w = pk2(v1.z, v1.w);
  return o;
}

// C = A @ B^T   A:[M,K] row-major, B:[N,K] row-major. AF32/BF32: operand dtype.
// MODE 0: L2-normalize each aligned 64-col group per row; Out = bf16 (u16*)
// MODE 1: add f32 bias[col]; Out = f32 (float*)
// Tiles: BM=BN=128, BK=32; 4 waves (2x2), per-wave 4x4 frags of 16x16x32 MFMA.
template <int MODE, int AF32, int BF32>
__global__ __launch_bounds__(256) void gemm_bt(
    const void* __restrict__ A_, const void* __restrict__ B_,
    const float* __restrict__ bias, void* __restrict__ Out_,
    int M, int Nn, int K) {
  __shared__ u16 As[128 * 32];
  __shared__ u16 Bs[128 * 32];
  const int tid = threadIdx.x;
  const int lane = tid & 63;
  const int w = tid >> 6;
  const int wm = w >> 1, wn = w & 1;
  const int tilesN = Nn >> 7;
  const int tm = blockIdx.x / tilesN;
  const int tn = blockIdx.x % tilesN;

  // staging: thread covers rows {tid>>2, tid>>2 + 64}, 8 elems (k) each
  const int srow = tid >> 2;           // [0,64)
  const int scol = (tid & 3) << 3;     // k element offset
  const size_t offA0 = (size_t)(tm * 128 + srow) * K + scol;
  const size_t offB0 = (size_t)(tn * 128 + srow) * K + scol;
  u16* sA0 = As + srow * 32 + scol;
  u16* sA1 = As + (srow + 64) * 32 + scol;
  u16* sB0 = Bs + srow * 32 + scol;
  u16* sB1 = Bs + (srow + 64) * 32 + scol;

  // fragment read bases: 16-dim index = lane&15, k-group = lane>>4 (same map A and B)
  const u16* rA = As + (wm * 64 + (lane & 15)) * 32 + ((lane >> 4) << 3);
  const u16* rB = Bs + (wn * 64 + (lane & 15)) * 32 + ((lane >> 4) << 3);

  f32x4 acc[4][4] = {};

  const int KT = K >> 5;
  for (int kt = 0; kt < KT; ++kt) {
    uint4 a0, a1, b0, b1;
    if (AF32) {
      const float* Af = (const float*)A_;
      a0 = cvt8(Af + offA0 + kt * 32);
      a1 = cvt8(Af + offA0 + kt * 32 + (size_t)64 * K);
    } else {
      const u16* Ab = (const u16*)A_;
      a0 = *(const uint4*)(Ab + offA0 + kt * 32);
      a1 = *(const uint4*)(Ab + offA0 + kt * 32 + (size_t)64 * K);
    }
    if (BF32) {
      const float* Bf = (const float*)B_;
      b0 = cvt8(Bf + offB0 + kt * 32);
      b1 = cvt8(Bf + offB0 + kt * 32 + (size_t)64 * K);
    } else {
      const u16* Bb = (const u16*)B_;
      b0 = *(const uint4*)(Bb + offB0 + kt * 32);
      b1 = *(const uint4*)(Bb + offB0 + kt * 32 + (size_t)64 * K);
    }
    __syncthreads();  // prior iteration's LDS reads all retired
    *(uint4*)sA0 = a0;
    *(uint4*)sA1 = a1;
    *(uint4*)sB0 = b0;
    *(uint4*)sB1 = b1;
    __syncthreads();  // staged tile visible to all waves
    bf16x8 af[4], bfr[4];
#pragma unroll
    for (int i = 0; i < 4; ++i) af[i] = *(const bf16x8*)(rA + i * 512);
#pragma unroll
    for (int i = 0; i < 4; ++i) bfr[i] = *(const bf16x8*)(rB + i * 512);
#pragma unroll
    for (int mi = 0; mi < 4; ++mi)
#pragma unroll
      for (int ni = 0; ni < 4; ++ni)
        acc[mi][ni] = __builtin_amdgcn_mfma_f32_16x16x32_bf16(af[mi], bfr[ni],
                                                              acc[mi][ni], 0, 0, 0);
  }

  // C/D layout (HW-verified m89/m91): col = lane&15, row = (lane>>4)*4 + r
  const int rowBase = tm * 128 + wm * 64 + ((lane >> 4) << 2);
  const int colBase = tn * 128 + wn * 64 + (lane & 15);

  if (MODE == 1) {
    float* Out = (float*)Out_;
    float bv[4];
#pragma unroll
    for (int ni = 0; ni < 4; ++ni) bv[ni] = bias[colBase + ni * 16];
#pragma unroll
    for (int mi = 0; mi < 4; ++mi)
#pragma unroll
      for (int r = 0; r < 4; ++r) {
        size_t ro = (size_t)(rowBase + mi * 16 + r) * Nn;
#pragma unroll
        for (int ni = 0; ni < 4; ++ni)
          Out[ro + colBase + ni * 16] = acc[mi][ni][r] + bv[ni];
      }
  } else {
    u16* Out = (u16*)Out_;
    // wave's 64 cols = exactly one aligned d=64 group; L2-normalize per row over them.
#pragma unroll
    for (int mi = 0; mi < 4; ++mi)
#pragma unroll
      for (int r = 0; r < 4; ++r) {
        float s = acc[mi][0][r] * acc[mi][0][r] + acc[mi][1][r] * acc[mi][1][r] +
                  acc[mi][2][r] * acc[mi][2][r] + acc[mi][3][r] * acc[mi][3][r];
        s += __shfl_xor(s, 1);
        s += __shfl_xor(s, 2);
        s += __shfl_xor(s, 4);
        s += __shfl_xor(s, 8);  // sum across the 16 lanes sharing lane>>4
        float inv = 1.0f / fmaxf(sqrtf(s), 1e-12f);
        size_t ro = (size_t)(rowBase + mi * 16 + r) * Nn;
#pragma unroll
        for (int ni = 0; ni < 4; ++ni)
          Out[ro + colBase + ni * 16] = f2bf(acc[mi][ni][r] * inv);
      }
  }
}

// Cost volume + fused 49->64 corr projection.
// qk: normalized [16384][1024] bf16 (cols 0..511 = q heads, 512..1023 = k heads)
// One thread per pixel+head. frame f = (b*8 + h)*8 + t; k from frame min(t+1,7).
__global__ __launch_bounds__(256) void costvol(
    const u16* __restrict__ qk, const float* __restrict__ wc,
    const float* __restrict__ bc, u16* __restrict__ mf) {
  __shared__ float wt[49 * 64];    // wt[p][dd] = w_corr[dd][p] (broadcast reads)
  __shared__ float bl[64];
  const int tid = threadIdx.x;
  for (int i = tid; i < 49 * 64; i += 256) {
    int p = i >> 6, dd = i & 63;
    wt[i] = wc[dd * 49 + p];
  }
  if (tid < 64) bl[tid] = bc[tid];
  __syncthreads();

  const int bid = blockIdx.x;
  const int f = bid >> 2;
  const int pix = ((bid & 3) << 8) + tid;
  const int t = f & 7, h = (f >> 3) & 7, bb = f >> 6;
  const int t1 = (t < 7) ? t + 1 : 7;
  const int y = pix >> 5, x = pix & 31;

  // q vector (64 channels) into registers
  const u16* qp = qk + ((size_t)((bb * 8 + t) * 1024 + pix)) * 1024 + h * 64;
  float q[64];
#pragma unroll
  for (int j = 0; j < 8; ++j) {
    uint4 v = *(const uint4*)(qp + j * 8);
    q[j * 8 + 0] = blo(v.x); q[j * 8 + 1] = bhi(v.x);
    q[j * 8 + 2] = blo(v.y); q[j * 8 + 3] = bhi(v.y);
    q[j * 8 + 4] = blo(v.z); q[j * 8 + 5] = bhi(v.z);
    q[j * 8 + 6] = blo(v.w); q[j * 8 + 7] = bhi(v.w);
  }

  f32x4 a4[16];
#pragma unroll
  for (int j = 0; j < 16; ++j) a4[j] = *(const f32x4*)&bl[j * 4];

  const u16* kb = qk + ((size_t)((bb * 8 + t1) * 1024)) * 1024 + 512 + h * 64;
#pragma unroll
  for (int du = 0; du < 7; ++du) {
    int yy = y + du - 3;
#pragma unroll
    for (int dv = 0; dv < 7; ++dv) {
      int xx = x + dv - 3;
      float s = 0.f;
      if ((unsigned)yy < 32u && (unsigned)xx < 32u) {
        const u16* kp = kb + (size_t)((yy << 5) + xx) * 1024;
#pragma unroll
        for (int j = 0; j < 8; ++j) {
          uint4 v = *(const uint4*)(kp + j * 8);
          s += q[j * 8 + 0] * blo(v.x) + q[j * 8 + 1] * bhi(v.x) +
               q[j * 8 + 2] * blo(v.y) + q[j * 8 + 3] * bhi(v.y) +
               q[j * 8 + 4] * blo(v.z) + q[j * 8 + 5] * bhi(v.z) +
               q[j * 8 + 6] * blo(v.w) + q[j * 8 + 7] * bhi(v.w);
        }
      }
      // fold 49->64 projection: a4 += s * w_corr[:, p]
      const float* wr = &wt[(du * 7 + dv) * 64];
#pragma unroll
      for (int j = 0; j < 16; ++j) {
        f32x4 w4 = *(const f32x4*)(wr + j * 4);
        a4[j] += s * w4;
      }
    }
  }

  u16* mp = mf + ((size_t)((bb * 8 + t) * 1024 + pix)) * 512 + h * 64;
#pragma unroll
  for (int j = 0; j < 8; ++j) {
    f32x4 v0 = a4[j * 2], v1 = a4[j * 2 + 1];
    uint4 o;
    o.x = pk2(v0.x, v0.y); o.y = pk2(v0.z, v0.w);
    o.z = pk2(v1.x, v1.y); o.w = pk2(v1.z, v1.w);
    *(uint4*)(mp + j * 8) = o;
  }
}

extern "C" void kernel_launch(void* const* d_in, const int* in_sizes, int n_in,
                              void* d_out, int out_size, void* d_ws, size_t ws_size,
                              hipStream_t stream) {
  const float* x      = (const float*)d_in[0];  // [2,8192,512] f32
  const float* w_qk   = (const float*)d_in[1];  // [1024,512]   f32
  const float* w_corr = (const float*)d_in[2];  // [64,49]      f32
  const float* b_corr = (const float*)d_in[3];  // [64]         f32
  const float* w_proj = (const float*)d_in[4];  // [512,512]    f32
  const float* b_proj = (const float*)d_in[5];  // [512]        f32
  float* out = (float*)d_out;                   // [2,8192,512] f32

  u16* qf = (u16*)d_ws;                      // [16384][1024] bf16 = 32MB
  u16* mf = qf + (size_t)16384 * 1024;       // [16384][512]  bf16 = 16MB

  // qk projection (f32 inputs, bf16 MFMA) + per-64-col L2 normalize
  gemm_bt<0, 1, 1><<<dim3(128 * 8), dim3(256), 0, stream>>>(
      x, w_qk, (const float*)nullptr, qf, 16384, 1024, 512);
  // cost volume + fused corr projection
  costvol<<<dim3(512), dim3(256), 0, stream>>>(qf, w_corr, b_corr, mf);
  // output projection + f32 bias, f32 output
  gemm_bt<1, 0, 1><<<dim3(128 * 4), dim3(256), 0, stream>>>(
      mf, w_proj, b_proj, out, 16384, 512, 512);
}

// Round 4
// 144.700 us; speedup vs baseline: 7.9986x; 7.9986x over previous
//
#include <hip/hip_runtime.h>
#include <hip/hip_bf16.h>

typedef unsigned int u32;
typedef unsigned short u16;
typedef short bf16x8 __attribute__((ext_vector_type(8)));
typedef float f32x4 __attribute__((ext_vector_type(4)));

#define DEVFN static __device__ __forceinline__

DEVFN u16 f2bf(float f) {
  u32 u = __builtin_bit_cast(u32, f);
  u = (u + 0x7fffu + ((u >> 16) & 1u)) >> 16;
  return (u16)u;
}
DEVFN u32 pk2(float a, float b) { return (u32)f2bf(a) | ((u32)f2bf(b) << 16); }
DEVFN float blo(u32 w) { return __builtin_bit_cast(float, w << 16); }
DEVFN float bhi(u32 w) { return __builtin_bit_cast(float, w & 0xffff0000u); }

// load 8 consecutive f32, pack to 8 bf16 (one uint4)
DEVFN uint4 cvt8(const float* p) {
  f32x4 v0 = *(const f32x4*)p;
  f32x4 v1 = *(const f32x4*)(p + 4);
  uint4 o;
  o.x = pk2(v0.x, v0.y); o.y = pk2(v0.z, v0.w);
  o.z = pk2(v1.x, v1.y); o.w = pk2(v1.z, v1.w);
  return o;
}

// C = A @ B^T. A:[M,K], B:[N,K] row-major.
// AF32/BF32: operand is f32 (convert while staging) else bf16.
// APLANAR: A is bf16 head-planar [bt*8+h][1024px][64] (mf layout); K=512.
// MODE 0: L2-normalize each aligned 64-col group; write bf16 PLANAR qf
//         [sel][b][t][h][1024px][64]  (frame idx fr = ((sel*2+b)*8+t)*8+h)
// MODE 1: add f32 bias[col]; Out = f32 row-major [M][Nn]
// Tiles: BM=BN=128, BK=32; 4 waves (2x2), per-wave 4x4 frags of 16x16x32 MFMA.
template <int MODE, int AF32, int BF32, int APLANAR>
__global__ __launch_bounds__(256) void gemm_bt(
    const void* __restrict__ A_, const void* __restrict__ B_,
    const float* __restrict__ bias, void* __restrict__ Out_,
    int M, int Nn, int K) {
  __shared__ u16 As[128 * 32];
  __shared__ u16 Bs[128 * 32];
  const int tid = threadIdx.x;
  const int lane = tid & 63;
  const int w = tid >> 6;
  const int wm = w >> 1, wn = w & 1;
  const int tilesN = Nn >> 7;
  const int tm = blockIdx.x / tilesN;
  const int tn = blockIdx.x % tilesN;

  // staging: thread covers rows {tid>>2, tid>>2 + 64}, 8 elems (k) each
  const int srow = tid >> 2;           // [0,64)
  const int scol = (tid & 3) << 3;     // k element offset within BK=32
  const size_t offA0 = (size_t)(tm * 128 + srow) * K + scol;
  const size_t offB0 = (size_t)(tn * 128 + srow) * K + scol;
  // planar-A precomputed pieces
  const int bt8 = (tm >> 3) << 3;            // bt*8
  const int px0 = (tm & 7) << 7;             // px base of tile
  u16* sA0 = As + srow * 32 + scol;
  u16* sA1 = As + (srow + 64) * 32 + scol;
  u16* sB0 = Bs + srow * 32 + scol;
  u16* sB1 = Bs + (srow + 64) * 32 + scol;

  // fragment read bases: 16-dim index = lane&15, k-group = lane>>4 (same map A,B)
  const u16* rA = As + (wm * 64 + (lane & 15)) * 32 + ((lane >> 4) << 3);
  const u16* rB = Bs + (wn * 64 + (lane & 15)) * 32 + ((lane >> 4) << 3);

  f32x4 acc[4][4] = {};

  const int KT = K >> 5;
  for (int kt = 0; kt < KT; ++kt) {
    uint4 a0, a1, b0, b1;
    if (APLANAR) {
      const u16* Ab = (const u16*)A_;
      size_t ab = (((size_t)(bt8 + (kt >> 1))) << 16) +
                  (size_t)(px0 + srow) * 64 + ((kt & 1) << 5) + scol;
      a0 = *(const uint4*)(Ab + ab);
      a1 = *(const uint4*)(Ab + ab + 64 * 64);
    } else if (AF32) {
      const float* Af = (const float*)A_;
      a0 = cvt8(Af + offA0 + kt * 32);
      a1 = cvt8(Af + offA0 + kt * 32 + (size_t)64 * K);
    } else {
      const u16* Ab = (const u16*)A_;
      a0 = *(const uint4*)(Ab + offA0 + kt * 32);
      a1 = *(const uint4*)(Ab + offA0 + kt * 32 + (size_t)64 * K);
    }
    if (BF32) {
      const float* Bf = (const float*)B_;
      b0 = cvt8(Bf + offB0 + kt * 32);
      b1 = cvt8(Bf + offB0 + kt * 32 + (size_t)64 * K);
    } else {
      const u16* Bb = (const u16*)B_;
      b0 = *(const uint4*)(Bb + offB0 + kt * 32);
      b1 = *(const uint4*)(Bb + offB0 + kt * 32 + (size_t)64 * K);
    }
    __syncthreads();  // prior iteration's LDS reads all retired
    *(uint4*)sA0 = a0;
    *(uint4*)sA1 = a1;
    *(uint4*)sB0 = b0;
    *(uint4*)sB1 = b1;
    __syncthreads();  // staged tile visible
    bf16x8 af[4], bfr[4];
#pragma unroll
    for (int i = 0; i < 4; ++i) af[i] = *(const bf16x8*)(rA + i * 512);
#pragma unroll
    for (int i = 0; i < 4; ++i) bfr[i] = *(const bf16x8*)(rB + i * 512);
#pragma unroll
    for (int mi = 0; mi < 4; ++mi)
#pragma unroll
      for (int ni = 0; ni < 4; ++ni)
        acc[mi][ni] = __builtin_amdgcn_mfma_f32_16x16x32_bf16(af[mi], bfr[ni],
                                                              acc[mi][ni], 0, 0, 0);
  }

  // C/D layout (HW-verified m89/m91): col = lane&15, row = (lane>>4)*4 + r
  const int rowBase = tm * 128 + wm * 64 + ((lane >> 4) << 2);
  const int colBase = tn * 128 + wn * 64 + (lane & 15);

  if (MODE == 1) {
    float* Out = (float*)Out_;
    float bv[4];
#pragma unroll
    for (int ni = 0; ni < 4; ++ni) bv[ni] = bias[colBase + ni * 16];
#pragma unroll
    for (int mi = 0; mi < 4; ++mi)
#pragma unroll
      for (int r = 0; r < 4; ++r) {
        size_t ro = (size_t)(rowBase + mi * 16 + r) * Nn;
#pragma unroll
        for (int ni = 0; ni < 4; ++ni)
          Out[ro + colBase + ni * 16] = acc[mi][ni][r] + bv[ni];
      }
  } else {
    u16* Out = (u16*)Out_;
    const int sel = colBase >> 9;
    const int hh = (colBase >> 6) & 7;
    const int ddb = lane & 15;
#pragma unroll
    for (int mi = 0; mi < 4; ++mi)
#pragma unroll
      for (int r = 0; r < 4; ++r) {
        float s = acc[mi][0][r] * acc[mi][0][r] + acc[mi][1][r] * acc[mi][1][r] +
                  acc[mi][2][r] * acc[mi][2][r] + acc[mi][3][r] * acc[mi][3][r];
        s += __shfl_xor(s, 1);
        s += __shfl_xor(s, 2);
        s += __shfl_xor(s, 4);
        s += __shfl_xor(s, 8);  // sum over the 16 lanes sharing lane>>4
        float inv = 1.0f / fmaxf(sqrtf(s), 1e-12f);
        const int m = rowBase + mi * 16 + r;
        const int bb = m >> 13, tt = (m >> 10) & 7, pix = m & 1023;
        const int fr = ((sel * 2 + bb) * 8 + tt) * 8 + hh;
        size_t base = (((size_t)fr) << 16) + (size_t)pix * 64 + ddb;
#pragma unroll
        for (int ni = 0; ni < 4; ++ni)
          Out[base + ni * 16] = f2bf(acc[mi][ni][r] * inv);
      }
  }
}

// Cost volume + fused 49->64 corr projection (planar layouts).
// qf planar: [sel][b][t][h][1024px][64] bf16.  mf planar: [(b*8+t)*8+h][1024px][64].
// Block = one (fr, row-group of 8 q-rows). 512 blocks x 256 threads.
__global__ __launch_bounds__(256) void costvol(
    const u16* __restrict__ qf, const float* __restrict__ wc,
    const float* __restrict__ bc, u16* __restrict__ mf) {
  __shared__ __align__(16) u16 kst[14 * 32 * 64];  // swizzled 128B rows, 56KB
  __shared__ __align__(16) u16 wtb[49 * 64];       // w_corr^T bf16, 6.1KB
  const int tid = threadIdx.x;
  const int bid = blockIdx.x;
  const int fr = bid >> 2, grp = bid & 3;
  const int h = fr & 7, t = (fr >> 3) & 7, b = fr >> 6;
  const int t1 = (t < 7) ? t + 1 : 7;
  const int y0 = grp * 8;

  // transpose w_corr [64][49] -> wtb[p][dd] bf16
  for (int i = tid; i < 49 * 64; i += 256) {
    int p = i >> 6, dd = i & 63;
    wtb[i] = f2bf(wc[dd * 49 + p]);
  }

  // stage k rows y0-3 .. y0+10 (zero-fill OOB rows), XOR-swizzled
  const u16* kbase = qf + (((size_t)(((2 + b) * 8 + t1) * 8 + h)) << 16);
#pragma unroll
  for (int pass = 0; pass < 14; ++pass) {
    int pl = pass * 32 + (tid >> 3);     // local px 0..447
    int inner = (tid & 7) << 4;          // byte col 0..112
    int gy = y0 - 3 + (pl >> 5);
    int gx = pl & 31;
    uint4 v = make_uint4(0, 0, 0, 0);
    if ((unsigned)gy < 32u)
      v = *(const uint4*)(kbase + (size_t)(gy * 32 + gx) * 64 + (inner >> 1));
    *(uint4*)((char*)kst + pl * 128 + (inner ^ ((pl & 7) << 4))) = v;
  }
  __syncthreads();

  // q vector into registers (coalesced: consecutive threads = consecutive px)
  const int px = grp * 256 + tid;
  const u16* qp = qf + (((size_t)fr) << 16) + (size_t)px * 64;
  float q[64];
#pragma unroll
  for (int j = 0; j < 8; ++j) {
    uint4 v = *(const uint4*)(qp + j * 8);
    q[j * 8 + 0] = blo(v.x); q[j * 8 + 1] = bhi(v.x);
    q[j * 8 + 2] = blo(v.y); q[j * 8 + 3] = bhi(v.y);
    q[j * 8 + 4] = blo(v.z); q[j * 8 + 5] = bhi(v.z);
    q[j * 8 + 6] = blo(v.w); q[j * 8 + 7] = bhi(v.w);
  }

  f32x4 a4[16];
#pragma unroll
  for (int j = 0; j < 16; ++j) a4[j] = *(const f32x4*)(bc + j * 4);

  const int ly = tid >> 5, lx = tid & 31;
  for (int du = 0; du < 7; ++du) {
    const int rl = ly + du;  // staged row 0..13 (OOB rows are zeros)
    for (int dv = 0; dv < 7; ++dv) {
      int xx = lx + dv - 3;
      int xc = xx < 0 ? 0 : (xx > 31 ? 31 : xx);
      int pl = rl * 32 + xc;
      const char* kr = (const char*)kst + pl * 128;
      const int sw = (pl & 7) << 4;
      float s0 = 0.f, s1 = 0.f, s2 = 0.f, s3 = 0.f;
#pragma unroll
      for (int j = 0; j < 8; ++j) {
        uint4 v = *(const uint4*)(kr + ((j * 16) ^ sw));
        s0 += q[j * 8 + 0] * blo(v.x) + q[j * 8 + 1] * bhi(v.x);
        s1 += q[j * 8 + 2] * blo(v.y) + q[j * 8 + 3] * bhi(v.y);
        s2 += q[j * 8 + 4] * blo(v.z) + q[j * 8 + 5] * bhi(v.z);
        s3 += q[j * 8 + 6] * blo(v.w) + q[j * 8 + 7] * bhi(v.w);
      }
      float s = (s0 + s1) + (s2 + s3);
      s = ((unsigned)xx < 32u) ? s : 0.f;   // OOB col -> 0 (no divergence)
      const u16* wr = wtb + (du * 7 + dv) * 64;
#pragma unroll
      for (int j = 0; j < 8; ++j) {
        uint4 wv = *(const uint4*)(wr + j * 8);  // broadcast read
        a4[j * 2 + 0].x += s * blo(wv.x); a4[j * 2 + 0].y += s * bhi(wv.x);
        a4[j * 2 + 0].z += s * blo(wv.y); a4[j * 2 + 0].w += s * bhi(wv.y);
        a4[j * 2 + 1].x += s * blo(wv.z); a4[j * 2 + 1].y += s * bhi(wv.z);
        a4[j * 2 + 1].z += s * blo(wv.w); a4[j * 2 + 1].w += s * bhi(wv.w);
      }
    }
  }

  u16* mp = mf + (((size_t)fr) << 16) + (size_t)px * 64;
#pragma unroll
  for (int j = 0; j < 8; ++j) {
    f32x4 v0 = a4[j * 2], v1 = a4[j * 2 + 1];
    uint4 o;
    o.x = pk2(v0.x, v0.y); o.y = pk2(v0.z, v0.w);
    o.z = pk2(v1.x, v1.y); o.w = pk2(v1.z, v1.w);
    *(uint4*)(mp + j * 8) = o;
  }
}

extern "C" void kernel_launch(void* const* d_in, const int* in_sizes, int n_in,
                              void* d_out, int out_size, void* d_ws, size_t ws_size,
                              hipStream_t stream) {
  const float* x      = (const float*)d_in[0];  // [2,8192,512] f32
  const float* w_qk   = (const float*)d_in[1];  // [1024,512]   f32
  const float* w_corr = (const float*)d_in[2];  // [64,49]      f32
  const float* b_corr = (const float*)d_in[3];  // [64]         f32
  const float* w_proj = (const float*)d_in[4];  // [512,512]    f32
  const float* b_proj = (const float*)d_in[5];  // [512]        f32
  float* out = (float*)d_out;                   // [2,8192,512] f32

  u16* qf = (u16*)d_ws;                      // planar [2][2][8][8][1024][64] = 32MB
  u16* mf = qf + (size_t)16384 * 1024;       // planar [128][1024][64]        = 16MB

  // qk projection (f32 in, bf16 MFMA) + per-head L2 norm, planar bf16 out
  gemm_bt<0, 1, 1, 0><<<dim3(128 * 8), dim3(256), 0, stream>>>(
      x, w_qk, (const float*)nullptr, qf, 16384, 1024, 512);
  // LDS-staged cost volume + fused corr projection
  costvol<<<dim3(512), dim3(256), 0, stream>>>(qf, w_corr, b_corr, mf);
  // output projection (planar bf16 A) + f32 bias, f32 out
  gemm_bt<1, 0, 1, 1><<<dim3(128 * 4), dim3(256), 0, stream>>>(
      mf, w_proj, b_proj, out, 16384, 512, 512);
}

// Round 6
// 108.646 us; speedup vs baseline: 10.6529x; 1.3318x over previous
//
#include <hip/hip_runtime.h>
#include <hip/hip_bf16.h>

typedef unsigned int u32;
typedef unsigned short u16;
typedef __fp16 h2 __attribute__((ext_vector_type(2)));
typedef __fp16 f16x8 __attribute__((ext_vector_type(8)));
typedef float f32x4 __attribute__((ext_vector_type(4)));

#define DEVFN static __device__ __forceinline__

// pack 2 f32 -> 2 f16 in one u32 (v_cvt_pkrtz_f16_f32)
DEVFN u32 pkh(float a, float b) {
  return __builtin_bit_cast(u32, __builtin_amdgcn_cvt_pkrtz(a, b));
}
DEVFN u16 f2h(float f) { __fp16 h = (__fp16)f; return __builtin_bit_cast(u16, h); }

#if __has_builtin(__builtin_amdgcn_fdot2)
DEVFN float dot2u(u32 a, u32 b, float c) {
  return __builtin_amdgcn_fdot2(__builtin_bit_cast(h2, a),
                                __builtin_bit_cast(h2, b), c, false);
}
#else
DEVFN float dot2u(u32 a, u32 b, float c) {
  h2 x = __builtin_bit_cast(h2, a), y = __builtin_bit_cast(h2, b);
  return c + (float)x[0] * (float)y[0] + (float)x[1] * (float)y[1];
}
#endif

// 8 consecutive f32 -> 8 f16 (one uint4)
DEVFN uint4 cvt8h(const float* p) {
  f32x4 v0 = *(const f32x4*)p;
  f32x4 v1 = *(const f32x4*)(p + 4);
  uint4 o;
  o.x = pkh(v0.x, v0.y); o.y = pkh(v0.z, v0.w);
  o.z = pkh(v1.x, v1.y); o.w = pkh(v1.z, v1.w);
  return o;
}

// async global->LDS, 16B/lane; LDS dest = wave-uniform base + lane*16 (HW contract)
DEVFN void gld16(const u16* g, u16* l) {
  __builtin_amdgcn_global_load_lds(
      (const __attribute__((address_space(1))) u32*)g,
      (__attribute__((address_space(3))) u32*)l, 16, 0, 0);
}

// f32 -> f16 pre-convert: x (8388608) -> xb, w_qk (524288) -> wqb
__global__ __launch_bounds__(256) void cvt3(
    const float* __restrict__ x, const float* __restrict__ wqk,
    u16* __restrict__ xb, u16* __restrict__ wqb) {
  const size_t e = ((size_t)blockIdx.x * 256 + threadIdx.x) * 8;
  const float* s;
  u16* d;
  if (e < 8388608) { s = x + e; d = xb + e; }
  else { s = wqk + (e - 8388608); d = wqb + (e - 8388608); }
  *(uint4*)d = cvt8h(s);
}

// C = A @ B^T, K=512. A f16 (row-major or planar), B f16 (gld16) or f32 (reg-cvt).
// MODE 0: L2-normalize each aligned 64-col group; write f16 PLANAR qf
//         [sel][b][t][h][1024px][64]  (fr = ((sel*2+b)*8+t)*8+h)
// MODE 1: add f32 bias[col]; Out = f32 row-major [M][Nn]
// Tiles: BM=BN=128, BK=32; 4 waves (2x2), per-wave 4x4 frags of mfma 16x16x32 f16.
template <int MODE, int APLANAR, int BF32, int TN>
__global__ __launch_bounds__(256) void gemm(
    const u16* __restrict__ A, const void* __restrict__ B_,
    const float* __restrict__ bias, void* __restrict__ Out_, int Nn) {
  const int K = 512;
  __shared__ u16 As[128 * 32];
  __shared__ u16 Bs[128 * 32];
  const int tid = threadIdx.x;
  const int lane = tid & 63;
  const int w = tid >> 6;
  const int wm = w >> 1, wn = w & 1;
  // bijective XCD swizzle (gridDim %8 == 0)
  const int nwg = (int)gridDim.x;
  const int wg = ((int)blockIdx.x & 7) * (nwg >> 3) + ((int)blockIdx.x >> 3);
  const int tm = wg / TN, tn = wg % TN;

  // gld16 staging geometry: wave w covers rows w*32..w*32+31, 2 calls of 16 rows
  const int sr = w * 32 + (lane >> 2);   // row within 128-tile
  const int sc = (lane & 3) << 3;        // k-elem offset (8 f16 = 16B)
  u16* lA = As + w * 1024;               // elems; byte base w*2048
  u16* lB = Bs + w * 1024;
  const u16* gA = A + (size_t)(tm * 128 + sr) * K + sc;       // !APLANAR
  const int bt8 = (tm >> 3) << 3, px0 = (tm & 7) << 7;        // APLANAR
  const u16* gB = (const u16*)B_ + (size_t)(tn * 128 + sr) * K + sc;  // !BF32
  // BF32 reg-staging geometry (per thread)
  const size_t offB0 = (size_t)(tn * 128 + (tid >> 2)) * K + ((tid & 3) << 3);
  u16* sB0 = Bs + (tid >> 2) * 32 + ((tid & 3) << 3);
  u16* sB1 = sB0 + 64 * 32;

  // fragment read bases: 16-dim idx = lane&15, k-group = lane>>4 (same map A,B)
  const u16* rA = As + (wm * 64 + (lane & 15)) * 32 + ((lane >> 4) << 3);
  const u16* rB = Bs + (wn * 64 + (lane & 15)) * 32 + ((lane >> 4) << 3);

  f32x4 acc[4][4] = {};

  for (int kt = 0; kt < 16; ++kt) {
    uint4 b0, b1;
    if (BF32) {
      const float* Bf = (const float*)B_;
      b0 = cvt8h(Bf + offB0 + kt * 32);
      b1 = cvt8h(Bf + offB0 + kt * 32 + (size_t)64 * K);
    }
    __syncthreads();  // prior iteration's LDS reads retired
    if (BF32) {
      *(uint4*)sB0 = b0;
      *(uint4*)sB1 = b1;
    } else {
      gld16(gB + kt * 32, lB);
      gld16(gB + kt * 32 + (size_t)16 * K, lB + 512);
    }
    if (APLANAR) {
      size_t ab = (((size_t)(bt8 + (kt >> 1))) << 16) +
                  (size_t)(px0 + sr) * 64 + ((kt & 1) << 5) + sc;
      gld16(A + ab, lA);
      gld16(A + ab + 1024, lA + 512);
    } else {
      gld16(gA + kt * 32, lA);
      gld16(gA + kt * 32 + (size_t)16 * K, lA + 512);
    }
    __syncthreads();  // compiler drains vmcnt+lgkmcnt before barrier
    f16x8 af[4], bf[4];
#pragma unroll
    for (int i = 0; i < 4; ++i) af[i] = *(const f16x8*)(rA + i * 512);
#pragma unroll
    for (int i = 0; i < 4; ++i) bf[i] = *(const f16x8*)(rB + i * 512);
#pragma unroll
    for (int mi = 0; mi < 4; ++mi)
#pragma unroll
      for (int ni = 0; ni < 4; ++ni)
        acc[mi][ni] = __builtin_amdgcn_mfma_f32_16x16x32_f16(af[mi], bf[ni],
                                                             acc[mi][ni], 0, 0, 0);
  }

  // C/D layout (HW-verified): col = lane&15, row = (lane>>4)*4 + r
  const int rowBase = tm * 128 + wm * 64 + ((lane >> 4) << 2);
  const int colBase = tn * 128 + wn * 64 + (lane & 15);

  if (MODE == 1) {
    float* Out = (float*)Out_;
    float bv[4];
#pragma unroll
    for (int ni = 0; ni < 4; ++ni) bv[ni] = bias[colBase + ni * 16];
#pragma unroll
    for (int mi = 0; mi < 4; ++mi)
#pragma unroll
      for (int r = 0; r < 4; ++r) {
        size_t ro = (size_t)(rowBase + mi * 16 + r) * Nn;
#pragma unroll
        for (int ni = 0; ni < 4; ++ni)
          Out[ro + colBase + ni * 16] = acc[mi][ni][r] + bv[ni];
      }
  } else {
    u16* Out = (u16*)Out_;
    const int sel = colBase >> 9;
    const int hh = (colBase >> 6) & 7;
    const int ddb = lane & 15;
#pragma unroll
    for (int mi = 0; mi < 4; ++mi)
#pragma unroll
      for (int r = 0; r < 4; ++r) {
        float s = acc[mi][0][r] * acc[mi][0][r] + acc[mi][1][r] * acc[mi][1][r] +
                  acc[mi][2][r] * acc[mi][2][r] + acc[mi][3][r] * acc[mi][3][r];
        s += __shfl_xor(s, 1);
        s += __shfl_xor(s, 2);
        s += __shfl_xor(s, 4);
        s += __shfl_xor(s, 8);  // sum over the 16 lanes sharing lane>>4
        float inv = 1.0f / fmaxf(sqrtf(s), 1e-12f);
        const int m = rowBase + mi * 16 + r;
        const int bb = m >> 13, tt = (m >> 10) & 7, pix = m & 1023;
        const int fr = ((sel * 2 + bb) * 8 + tt) * 8 + hh;
        size_t base = (((size_t)fr) << 16) + (size_t)pix * 64 + ddb;
#pragma unroll
        for (int ni = 0; ni < 4; ++ni)
          Out[base + ni * 16] = f2h(acc[mi][ni][r] * inv);
      }
  }
}

// one (du,dv) dot: 8 swizzled b128 LDS reads + 32 v_dot2_f32_f16
#define KDOT(OUTV, DV)                                                     \
  {                                                                        \
    int xx = lx + (DV)-3;                                                  \
    int xc = xx < 0 ? 0 : (xx > 31 ? 31 : xx);                             \
    int pl = rl * 32 + xc;                                                 \
    const char* kr = (const char*)kst + pl * 128;                          \
    const int swz = (pl & 7) << 4;                                         \
    float s0 = 0.f, s1 = 0.f, s2 = 0.f, s3 = 0.f;                          \
    _Pragma("unroll") for (int j = 0; j < 8; ++j) {                        \
      uint4 v = *(const uint4*)(kr + ((j * 16) ^ swz));                    \
      s0 = dot2u(qw[j * 4 + 0], v.x, s0);                                  \
      s1 = dot2u(qw[j * 4 + 1], v.y, s1);                                  \
      s2 = dot2u(qw[j * 4 + 2], v.z, s2);                                  \
      s3 = dot2u(qw[j * 4 + 3], v.w, s3);                                  \
    }                                                                      \
    float sres = (s0 + s1) + (s2 + s3);                                    \
    OUTV = ((unsigned)xx < 32u) ? sres : 0.f;                              \
  }

// Cost volume + fused 49->64 corr projection (all f16 via dot2).
// qf planar [sel][b][t][h][1024px][64] f16.  mf planar [(b*8+t)*8+h][1024px][64].
// Block = (fr, 8-row group); 512 blocks x 256 threads, 1 thread/px.
__global__ __launch_bounds__(256) void costvol(
    const u16* __restrict__ qf, const float* __restrict__ wc,
    const float* __restrict__ bcr, u16* __restrict__ mf) {
  __shared__ __align__(16) u16 kst[448 * 64];   // 14 k-rows x 32 px x 128B, swizzled
  __shared__ __align__(16) u32 wpr[28 * 64];    // w pairs: [du*4+dvp][dd] = (w[uv],w[uv+1])
  const int tid = threadIdx.x;
  const int bid = ((int)blockIdx.x & 7) * 64 + ((int)blockIdx.x >> 3);  // XCD swizzle
  const int fr = bid >> 2, grp = bid & 3;
  const int h = fr & 7, t = (fr >> 3) & 7, b = fr >> 6;
  const int t1 = (t < 7) ? t + 1 : 7;
  const int y0 = grp * 8;

  // pack w_corr columns into (dv,dv+1) pairs; dvp==3 pairs (dv=6, zero)
  for (int i = tid; i < 28 * 64; i += 256) {
    int pd = i >> 6, dd = i & 63;
    int uv0 = (pd >> 2) * 7 + (pd & 3) * 2;
    float w0 = wc[dd * 49 + uv0];
    float w1 = ((pd & 3) < 3) ? wc[dd * 49 + uv0 + 1] : 0.f;
    wpr[i] = pkh(w0, w1);
  }

  // stage 14 k-rows (zero-fill OOB), XOR-swizzled 128B rows
  const u16* kbase = qf + (((size_t)(((2 + b) * 8 + t1) * 8 + h)) << 16);
#pragma unroll
  for (int pass = 0; pass < 14; ++pass) {
    int pl = pass * 32 + (tid >> 3);
    int inner = (tid & 7) << 4;
    int gy = y0 - 3 + (pl >> 5), gx = pl & 31;
    uint4 v = make_uint4(0, 0, 0, 0);
    if ((unsigned)gy < 32u)
      v = *(const uint4*)(kbase + (size_t)(gy * 32 + gx) * 64 + (inner >> 1));
    *(uint4*)((char*)kst + pl * 128 + (inner ^ ((pl & 7) << 4))) = v;
  }
  __syncthreads();

  const int px = grp * 256 + tid;
  const u16* qp = qf + (((size_t)fr) << 16) + (size_t)px * 64;
  u32 qw[32];
#pragma unroll
  for (int j = 0; j < 8; ++j) {
    uint4 v = *(const uint4*)(qp + j * 8);
    qw[j * 4 + 0] = v.x; qw[j * 4 + 1] = v.y;
    qw[j * 4 + 2] = v.z; qw[j * 4 + 3] = v.w;
  }

  f32x4 a4[16];
#pragma unroll
  for (int j = 0; j < 16; ++j) a4[j] = *(const f32x4*)(bcr + j * 4);

  const int ly = tid >> 5, lx = tid & 31;
  for (int du = 0; du < 7; ++du) {   // rolled: small I$
    const int rl = ly + du;
#pragma unroll
    for (int dvp = 0; dvp < 4; ++dvp) {
      float s0v, s1v;
      KDOT(s0v, dvp * 2)
      if (dvp < 3) { KDOT(s1v, dvp * 2 + 1) }
      else s1v = 0.f;
      const u32 sp = pkh(s0v, s1v);
      const u32* wr = wpr + (du * 4 + dvp) * 64;
#pragma unroll
      for (int j = 0; j < 16; ++j) {   // fold pair into 64 dd accumulators
        uint4 wv = *(const uint4*)(wr + j * 4);
        a4[j].x = dot2u(sp, wv.x, a4[j].x);
        a4[j].y = dot2u(sp, wv.y, a4[j].y);
        a4[j].z = dot2u(sp, wv.z, a4[j].z);
        a4[j].w = dot2u(sp, wv.w, a4[j].w);
      }
    }
  }

  u16* mp = mf + (((size_t)fr) << 16) + (size_t)px * 64;
#pragma unroll
  for (int j = 0; j < 8; ++j) {
    f32x4 v0 = a4[j * 2], v1 = a4[j * 2 + 1];
    uint4 o;
    o.x = pkh(v0.x, v0.y); o.y = pkh(v0.z, v0.w);
    o.z = pkh(v1.x, v1.y); o.w = pkh(v1.z, v1.w);
    *(uint4*)(mp + j * 8) = o;
  }
}

extern "C" void kernel_launch(void* const* d_in, const int* in_sizes, int n_in,
                              void* d_out, int out_size, void* d_ws, size_t ws_size,
                              hipStream_t stream) {
  const float* x      = (const float*)d_in[0];  // [2,8192,512] f32
  const float* w_qk   = (const float*)d_in[1];  // [1024,512]   f32
  const float* w_corr = (const float*)d_in[2];  // [64,49]      f32
  const float* b_corr = (const float*)d_in[3];  // [64]         f32
  const float* w_proj = (const float*)d_in[4];  // [512,512]    f32
  const float* b_proj = (const float*)d_in[5];  // [512]        f32
  float* out = (float*)d_out;                   // [2,8192,512] f32

  // ws (48MB): [0,16MB) xb (f16 x), later aliased by mf; [16MB,48MB) qf
  u16* xb = (u16*)d_ws;
  u16* mf = xb;                                // alias: xb dead after GEMM1
  u16* qf = xb + (size_t)16384 * 512;
  u16* wqb = (u16*)d_out;                      // 1MB scratch; overwritten by GEMM2

  // f32 -> f16 conversions (x -> ws, w_qk -> d_out scratch)
  cvt3<<<dim3(4352), dim3(256), 0, stream>>>(x, w_qk, xb, wqb);
  // qk projection + per-head L2 norm -> planar f16 qf
  gemm<0, 0, 0, 8><<<dim3(1024), dim3(256), 0, stream>>>(
      xb, wqb, (const float*)nullptr, qf, 1024);
  // cost volume + fused corr projection (writes mf over xb region)
  costvol<<<dim3(512), dim3(256), 0, stream>>>(qf, w_corr, b_corr, mf);
  // output projection (planar f16 A via gld16, f32 B reg-cvt) + bias, f32 out
  gemm<1, 1, 1, 4><<<dim3(512), dim3(256), 0, stream>>>(
      mf, w_proj, b_proj, out, 512);
}